// Round 5
// baseline (726.227 us; speedup 1.0000x reference)
//
#include <hip/hip_runtime.h>
#include <math.h>

#define NN 100000
#define NE 1600000
#define EPS_BN 1e-5f
#define EPS_NORM 1e-12f
#define SLOPE 0.01f
#define STATS_BLOCKS 512
#define SCAN_BLOCKS ((NN + 255) / 256)   // 391

__device__ __forceinline__ float fast_tanh(float x) {
    // tanh(x) = 1 - 2/(exp2(x*2*log2e)+1); exact saturation at +-inf
    float t = exp2f(x * 2.885390082f);
    return fmaf(-2.0f, __builtin_amdgcn_rcpf(t + 1.0f), 1.0f);
}

// Pass 1: e-moment partials (77 scalars/block) + in-degree.
__global__ void __launch_bounds__(256) stats_kernel(
    const float* __restrict__ v,
    const int* __restrict__ ei,
    const float* __restrict__ ea,
    float* __restrict__ partials,   // [STATS_BLOCKS][77]
    int* __restrict__ deg)          // [NN] (pre-zeroed)
{
    float acc[77];
#pragma unroll
    for (int i = 0; i < 77; ++i) acc[i] = 0.0f;

    int tid = blockIdx.x * blockDim.x + threadIdx.x;
    int stride = gridDim.x * blockDim.x;
    for (int eidx = tid; eidx < NE; eidx += stride) {
        int s = ei[eidx];
        int d = ei[NE + eidx];
        atomicAdd(&deg[d], 1);

        float e[11];
        float2 a2 = *(const float2*)(ea + 2 * (size_t)eidx);
        e[0] = a2.x;
        e[1] = a2.y;
        float4 s0 = *(const float4*)(v + (size_t)s * 8);
        float4 s1 = *(const float4*)(v + (size_t)s * 8 + 4);
        float4 d0 = *(const float4*)(v + (size_t)d * 8);
        float4 d1 = *(const float4*)(v + (size_t)d * 8 + 4);
        float df[8];
        df[0] = d0.x - s0.x; df[1] = d0.y - s0.y;
        df[2] = d0.z - s0.z; df[3] = d0.w - s0.w;
        df[4] = d1.x - s1.x; df[5] = d1.y - s1.y;
        df[6] = d1.z - s1.z; df[7] = d1.w - s1.w;
        float nsq = 0.0f;
#pragma unroll
        for (int i = 0; i < 8; ++i) nsq = fmaf(df[i], df[i], nsq);
        float nrm = sqrtf(nsq);
        e[2] = nrm;
        float inv = __builtin_amdgcn_rcpf(nrm + EPS_NORM);
#pragma unroll
        for (int i = 0; i < 8; ++i) e[3 + i] = df[i] * inv;

        int p = 11;
#pragma unroll
        for (int k = 0; k < 11; ++k) {
            acc[k] += e[k];
#pragma unroll
            for (int l = k; l < 11; ++l) { acc[p] = fmaf(e[k], e[l], acc[p]); ++p; }
        }
    }

#pragma unroll
    for (int i = 0; i < 77; ++i) {
        float x = acc[i];
        for (int off = 32; off > 0; off >>= 1) x += __shfl_down(x, off);
        acc[i] = x;
    }
    __shared__ float lsum[4][77];
    int wave = threadIdx.x >> 6;
    int lane = threadIdx.x & 63;
    if (lane == 0) {
#pragma unroll
        for (int i = 0; i < 77; ++i) lsum[wave][i] = acc[i];
    }
    __syncthreads();
    if (threadIdx.x < 77) {
        float t = lsum[0][threadIdx.x] + lsum[1][threadIdx.x]
                + lsum[2][threadIdx.x] + lsum[3][threadIdx.x];
        partials[blockIdx.x * 77 + threadIdx.x] = t;
    }
}

// Pass 2: reduce partials, closed-form BN, fold scale into W' and b'.
__global__ void bn_finalize_kernel(
    const float* __restrict__ partials,
    const float* __restrict__ w0, const float* __restrict__ b0,
    const float* __restrict__ g0, const float* __restrict__ be0,
    const float* __restrict__ w1, const float* __restrict__ b1,
    const float* __restrict__ g1, const float* __restrict__ be1,
    float* __restrict__ wbp)   // layer l at +l*768: W'[704] then b'[64]
{
    __shared__ double gs[77];
    int t = threadIdx.x;
    if (t < 77) {
        double s = 0.0;
        for (int b = 0; b < STATS_BLOCKS; ++b) s += (double)partials[b * 77 + t];
        gs[t] = s;
    }
    __syncthreads();
    if (t >= 128) return;
    int layer = t >> 6;
    int c = t & 63;
    const float* W  = layer ? w1 : w0;
    const float* B  = layer ? b1 : b0;
    const float* G  = layer ? g1 : g0;
    const float* BE = layer ? be1 : be0;

    const double invE = 1.0 / (double)NE;
    double m[11], wv[11];
    for (int k = 0; k < 11; ++k) {
        m[k] = gs[k] * invE;
        wv[k] = (double)W[k * 64 + c];
    }
    double md = 0.0;
    for (int k = 0; k < 11; ++k) md += m[k] * wv[k];
    double s2 = 0.0;
    int p = 11;
    for (int k = 0; k < 11; ++k)
        for (int l = k; l < 11; ++l) {
            double Me = gs[p] * invE; ++p;
            double term = Me * wv[k] * wv[l];
            s2 += (k == l) ? term : 2.0 * term;
        }
    double var = s2 - md * md;
    double mu = md + (double)B[c];
    float scale = (float)((double)G[c] / sqrt(var + (double)EPS_BN));
    float shift = (float)((double)BE[c] - mu * (double)scale);

    float* wpd = wbp + layer * 768;
    for (int k = 0; k < 11; ++k) wpd[k * 64 + c] = W[k * 64 + c] * scale;
    wpd[704 + c] = fmaf(B[c], scale, shift);
}

// Pass 3a: per-block exclusive scan of deg -> rowptr (block-local) + block sums.
__global__ void __launch_bounds__(256) scanA_kernel(
    const int* __restrict__ deg, int* __restrict__ rowptr, int* __restrict__ bsum)
{
    int b = blockIdx.x, t = threadIdx.x;
    int i = b * 256 + t;
    int d = (i < NN) ? deg[i] : 0;
    __shared__ int sh[256];
    sh[t] = d;
    __syncthreads();
    for (int off = 1; off < 256; off <<= 1) {
        int val = (t >= off) ? sh[t - off] : 0;
        __syncthreads();
        sh[t] += val;
        __syncthreads();
    }
    if (i < NN) rowptr[i] = sh[t] - d;     // exclusive within block
    if (t == 255) bsum[b] = sh[255];
}

// Pass 3b: add block offsets in-place.
__global__ void __launch_bounds__(256) scanC_kernel(
    int* __restrict__ rowptr, const int* __restrict__ bsum)
{
    int b = blockIdx.x, t = threadIdx.x;
    __shared__ int sh[256];
    int s = 0;
    for (int j = t; j < b; j += 256) s += bsum[j];
    sh[t] = s;
    __syncthreads();
    for (int off = 128; off > 0; off >>= 1) {
        if (t < off) sh[t] += sh[t + off];
        __syncthreads();
    }
    int boff = sh[0];
    int i = b * 256 + t;
    if (i < NN) rowptr[i] += boff;
    if (b == 0 && t == 0) rowptr[NN] = NE;
}

// Pass 4: scatter edge records (src + bf16-packed edge_attr) into dst order.
__global__ void __launch_bounds__(256) scatter_kernel(
    const int* __restrict__ ei, const float* __restrict__ ea,
    int* __restrict__ cursor, int2* __restrict__ recs)
{
    int e = blockIdx.x * 256 + threadIdx.x;
    if (e >= NE) return;
    int s = ei[e];
    int d = ei[NE + e];
    float2 a2 = *(const float2*)(ea + 2 * (size_t)e);
    unsigned ua = __float_as_uint(a2.x), ub = __float_as_uint(a2.y);
    unsigned pa = (ua + 0x7fffu + ((ua >> 16) & 1u)) >> 16;   // rne bf16
    unsigned pb = (ub + 0x7fffu + ((ub >> 16) & 1u)) >> 16;
    int idx = atomicAdd(&cursor[d], 1);
    recs[idx] = make_int2(s, (int)((pa << 16) | pb));
}

// Degree-bucket counting sort: nodes grouped by min(deg,63) so the 8
// node-groups sharing a wave have near-equal trip counts.
__global__ void __launch_bounds__(256) bucket_kernel(
    const int* __restrict__ rowptr, int* __restrict__ hist, int* __restrict__ pr)
{
    int n = blockIdx.x * 256 + threadIdx.x;
    if (n >= NN) return;
    int d = rowptr[n + 1] - rowptr[n];
    int b = d < 63 ? d : 63;
    int r = atomicAdd(&hist[b], 1);
    pr[n] = (r << 6) | b;
}

__global__ void scan64_kernel(const int* __restrict__ hist, int* __restrict__ boff)
{
    int t = threadIdx.x;   // 64
    int v = hist[t];
    int s = v;
    for (int off = 1; off < 64; off <<= 1) {
        int u = __shfl_up(s, off);
        if (t >= off) s += u;
    }
    boff[t] = s - v;
}

__global__ void __launch_bounds__(256) perm_kernel(
    const int* __restrict__ pr, const int* __restrict__ boff, int* __restrict__ perm)
{
    int n = blockIdx.x * 256 + threadIdx.x;
    if (n >= NN) return;
    int p = pr[n];
    perm[boff[p & 63] + (p >> 6)] = n;
}

// Pass 5 (per layer): fused gather-message + mean + root + lrelu (+residual).
// 8 threads per dst node (degree-sorted); weights in registers.
template<int LAYER>
__global__ void __launch_bounds__(256) layer_kernel(
    const float* __restrict__ vres,
    const float* __restrict__ x,       // v for L0, v1 for L1
    const int2* __restrict__ recs,
    const int* __restrict__ rowptr,
    const int* __restrict__ perm,
    const float* __restrict__ wb,      // [768] W' then b'
    const float* __restrict__ rw, const float* __restrict__ rb,
    float* __restrict__ out)
{
    int g = blockIdx.x * 256 + threadIdx.x;   // g < 8*NN exactly
    int n = perm[g >> 3];
    int i = g & 7;

    float wreg[11][8];
#pragma unroll
    for (int k = 0; k < 11; ++k) {
        float4 wa = *(const float4*)(wb + k * 64 + i * 8);
        float4 wc = *(const float4*)(wb + k * 64 + i * 8 + 4);
        wreg[k][0] = wa.x; wreg[k][1] = wa.y; wreg[k][2] = wa.z; wreg[k][3] = wa.w;
        wreg[k][4] = wc.x; wreg[k][5] = wc.y; wreg[k][6] = wc.z; wreg[k][7] = wc.w;
    }
    float breg[8];
    {
        float4 ba = *(const float4*)(wb + 704 + i * 8);
        float4 bb = *(const float4*)(wb + 704 + i * 8 + 4);
        breg[0] = ba.x; breg[1] = ba.y; breg[2] = ba.z; breg[3] = ba.w;
        breg[4] = bb.x; breg[5] = bb.y; breg[6] = bb.z; breg[7] = bb.w;
    }

    float4 vd0 = *(const float4*)(vres + (size_t)n * 8);
    float4 vd1 = *(const float4*)(vres + (size_t)n * 8 + 4);
    float vd[8] = {vd0.x, vd0.y, vd0.z, vd0.w, vd1.x, vd1.y, vd1.z, vd1.w};

    float msg[8];
#pragma unroll
    for (int o = 0; o < 8; ++o) msg[o] = 0.0f;

    int rp0 = rowptr[n];
    int rp1 = rowptr[n + 1];
    for (int j = rp0; j < rp1; ++j) {
        int2 r = recs[j];
        int s = r.x;
        unsigned p = (unsigned)r.y;
        float e[11];
        e[0] = __uint_as_float(p & 0xffff0000u);
        e[1] = __uint_as_float(p << 16);
        float4 s0 = *(const float4*)(vres + (size_t)s * 8);
        float4 s1 = *(const float4*)(vres + (size_t)s * 8 + 4);
        float xi = x[(size_t)s * 8 + i];

        float df[8];
        df[0] = vd[0] - s0.x; df[1] = vd[1] - s0.y;
        df[2] = vd[2] - s0.z; df[3] = vd[3] - s0.w;
        df[4] = vd[4] - s1.x; df[5] = vd[5] - s1.y;
        df[6] = vd[6] - s1.z; df[7] = vd[7] - s1.w;
        float nsq = 0.0f;
#pragma unroll
        for (int q = 0; q < 8; ++q) nsq = fmaf(df[q], df[q], nsq);
        float nrm = sqrtf(nsq);
        float invn = __builtin_amdgcn_rcpf(nrm + EPS_NORM);
        e[2] = nrm;
#pragma unroll
        for (int q = 0; q < 8; ++q) e[3 + q] = df[q] * invn;

#pragma unroll
        for (int o = 0; o < 8; ++o) {
            float hh = breg[o];
#pragma unroll
            for (int k = 0; k < 11; ++k) hh = fmaf(e[k], wreg[k][o], hh);
            msg[o] = fmaf(xi, fast_tanh(hh), msg[o]);
        }
    }

    // sum partial msg over the 8 lanes of this node-group
#pragma unroll
    for (int o = 0; o < 8; ++o) {
        float m = msg[o];
        m += __shfl_xor(m, 1);
        m += __shfl_xor(m, 2);
        m += __shfl_xor(m, 4);
        msg[o] = m;
    }
    float mo = msg[0];
#pragma unroll
    for (int o = 1; o < 8; ++o) if (i == o) mo = msg[o];

    float cf = (float)(rp1 - rp0);
    float invc = __builtin_amdgcn_rcpf(fmaxf(cf, 1.0f));

    float xn[8];
    if (LAYER == 0) {
#pragma unroll
        for (int q = 0; q < 8; ++q) xn[q] = vd[q];
    } else {
        float4 x0 = *(const float4*)(x + (size_t)n * 8);
        float4 x1 = *(const float4*)(x + (size_t)n * 8 + 4);
        xn[0] = x0.x; xn[1] = x0.y; xn[2] = x0.z; xn[3] = x0.w;
        xn[4] = x1.x; xn[5] = x1.y; xn[6] = x1.z; xn[7] = x1.w;
    }
    float a = fmaf(mo, invc, rb[i]);
#pragma unroll
    for (int k = 0; k < 8; ++k) a = fmaf(xn[k], rw[k * 8 + i], a);
    float y = (a > 0.0f) ? a : SLOPE * a;
    if (LAYER == 1) y += vres[(size_t)n * 8 + i];
    out[(size_t)n * 8 + i] = y;
}

extern "C" void kernel_launch(void* const* d_in, const int* in_sizes, int n_in,
                              void* d_out, int out_size, void* d_ws, size_t ws_size,
                              hipStream_t stream) {
    const float* v  = (const float*)d_in[0];
    const int* ei   = (const int*)d_in[1];
    const float* ea = (const float*)d_in[2];
    const float* en_w0  = (const float*)d_in[3];
    const float* en_b0  = (const float*)d_in[4];
    const float* en_g0  = (const float*)d_in[5];
    const float* en_be0 = (const float*)d_in[6];
    const float* rw0    = (const float*)d_in[7];
    const float* rb0    = (const float*)d_in[8];
    const float* en_w1  = (const float*)d_in[9];
    const float* en_b1  = (const float*)d_in[10];
    const float* en_g1  = (const float*)d_in[11];
    const float* en_be1 = (const float*)d_in[12];
    const float* rw1    = (const float*)d_in[13];
    const float* rb1    = (const float*)d_in[14];

    char* ws = (char*)d_ws;
    float* partials = (float*)(ws);                   // 157,696 B
    float* wbp      = (float*)(ws + 163840);          // 6,144 B
    int*   deg      = (int*)  (ws + 172032);          // 400,000 B
    int*   hist     = (int*)  (ws + 572032);          // 256 B (memset with deg)
    int*   boff     = (int*)  (ws + 572416);          // 256 B
    int*   rowptr   = (int*)  (ws + 573440);          // 400,004 B
    int*   bsum     = (int*)  (ws + 974848);          // 1,564 B
    int*   pr       = (int*)  (ws + 976896);          // 400,000 B
    int*   perm     = (int*)  (ws + 1377280);         // 400,000 B
    int*   cursor   = (int*)  (ws + 1777664);         // 400,000 B
    float* v1       = (float*)(ws + 2179072);         // 3,200,000 B
    int2*  recs     = (int2*) (ws + 5380096);         // 12,800,000 B (end ~18.2 MB)
    float* vout     = (float*)d_out;

    hipMemsetAsync(deg, 0, 400384, stream);   // deg + hist

    stats_kernel<<<STATS_BLOCKS, 256, 0, stream>>>(v, ei, ea, partials, deg);
    bn_finalize_kernel<<<1, 128, 0, stream>>>(partials, en_w0, en_b0, en_g0, en_be0,
                                              en_w1, en_b1, en_g1, en_be1, wbp);
    scanA_kernel<<<SCAN_BLOCKS, 256, 0, stream>>>(deg, rowptr, bsum);
    scanC_kernel<<<SCAN_BLOCKS, 256, 0, stream>>>(rowptr, bsum);
    hipMemcpyAsync(cursor, rowptr, NN * sizeof(int), hipMemcpyDeviceToDevice, stream);
    scatter_kernel<<<(NE + 255) / 256, 256, 0, stream>>>(ei, ea, cursor, recs);
    bucket_kernel<<<SCAN_BLOCKS, 256, 0, stream>>>(rowptr, hist, pr);
    scan64_kernel<<<1, 64, 0, stream>>>(hist, boff);
    perm_kernel<<<SCAN_BLOCKS, 256, 0, stream>>>(pr, boff, perm);

    const int LB = (NN * 8) / 256;   // 3125, exact
    layer_kernel<0><<<LB, 256, 0, stream>>>(v, v,  recs, rowptr, perm, wbp,       rw0, rb0, v1);
    layer_kernel<1><<<LB, 256, 0, stream>>>(v, v1, recs, rowptr, perm, wbp + 768, rw1, rb1, vout);
}

// Round 6
// 460.780 us; speedup vs baseline: 1.5761x; 1.5761x over previous
//
#include <hip/hip_runtime.h>
#include <math.h>

#define NN 100000
#define NE 1600000
#define EPS_BN 1e-5f
#define EPS_NORM 1e-12f
#define SLOPE 0.01f
#define STATS_BLOCKS 512
#define SCAN_BLOCKS ((NN + 255) / 256)       // 391
#define GS_LEN (64 * SCAN_BLOCKS)            // 25024
#define GS_BLOCKS ((GS_LEN + 255) / 256)     // 98

__device__ __forceinline__ float fast_tanh(float x) {
    // tanh(x) = 1 - 2/(exp2(x*2*log2e)+1); exact saturation at +-inf
    float t = exp2f(x * 2.885390082f);
    return fmaf(-2.0f, __builtin_amdgcn_rcpf(t + 1.0f), 1.0f);
}

// Pass 1: e-moment partials (77 scalars/block) + in-degree.
__global__ void __launch_bounds__(256) stats_kernel(
    const float* __restrict__ v,
    const int* __restrict__ ei,
    const float* __restrict__ ea,
    float* __restrict__ partials,   // [STATS_BLOCKS][77]
    int* __restrict__ deg)          // [NN] (pre-zeroed)
{
    float acc[77];
#pragma unroll
    for (int i = 0; i < 77; ++i) acc[i] = 0.0f;

    int tid = blockIdx.x * blockDim.x + threadIdx.x;
    int stride = gridDim.x * blockDim.x;
    for (int eidx = tid; eidx < NE; eidx += stride) {
        int s = ei[eidx];
        int d = ei[NE + eidx];
        atomicAdd(&deg[d], 1);

        float e[11];
        float2 a2 = *(const float2*)(ea + 2 * (size_t)eidx);
        e[0] = a2.x;
        e[1] = a2.y;
        float4 s0 = *(const float4*)(v + (size_t)s * 8);
        float4 s1 = *(const float4*)(v + (size_t)s * 8 + 4);
        float4 d0 = *(const float4*)(v + (size_t)d * 8);
        float4 d1 = *(const float4*)(v + (size_t)d * 8 + 4);
        float df[8];
        df[0] = d0.x - s0.x; df[1] = d0.y - s0.y;
        df[2] = d0.z - s0.z; df[3] = d0.w - s0.w;
        df[4] = d1.x - s1.x; df[5] = d1.y - s1.y;
        df[6] = d1.z - s1.z; df[7] = d1.w - s1.w;
        float nsq = 0.0f;
#pragma unroll
        for (int i = 0; i < 8; ++i) nsq = fmaf(df[i], df[i], nsq);
        float nrm = sqrtf(nsq);
        e[2] = nrm;
        float inv = __builtin_amdgcn_rcpf(nrm + EPS_NORM);
#pragma unroll
        for (int i = 0; i < 8; ++i) e[3 + i] = df[i] * inv;

        int p = 11;
#pragma unroll
        for (int k = 0; k < 11; ++k) {
            acc[k] += e[k];
#pragma unroll
            for (int l = k; l < 11; ++l) { acc[p] = fmaf(e[k], e[l], acc[p]); ++p; }
        }
    }

#pragma unroll
    for (int i = 0; i < 77; ++i) {
        float x = acc[i];
        for (int off = 32; off > 0; off >>= 1) x += __shfl_down(x, off);
        acc[i] = x;
    }
    __shared__ float lsum[4][77];
    int wave = threadIdx.x >> 6;
    int lane = threadIdx.x & 63;
    if (lane == 0) {
#pragma unroll
        for (int i = 0; i < 77; ++i) lsum[wave][i] = acc[i];
    }
    __syncthreads();
    if (threadIdx.x < 77) {
        float t = lsum[0][threadIdx.x] + lsum[1][threadIdx.x]
                + lsum[2][threadIdx.x] + lsum[3][threadIdx.x];
        partials[blockIdx.x * 77 + threadIdx.x] = t;
    }
}

// Pass 2: reduce partials, closed-form BN, fold scale into W' and b'.
__global__ void bn_finalize_kernel(
    const float* __restrict__ partials,
    const float* __restrict__ w0, const float* __restrict__ b0,
    const float* __restrict__ g0, const float* __restrict__ be0,
    const float* __restrict__ w1, const float* __restrict__ b1,
    const float* __restrict__ g1, const float* __restrict__ be1,
    float* __restrict__ wbp)   // layer l at +l*768: W'[704] then b'[64]
{
    __shared__ double gs[77];
    int t = threadIdx.x;
    if (t < 77) {
        double s = 0.0;
        for (int b = 0; b < STATS_BLOCKS; ++b) s += (double)partials[b * 77 + t];
        gs[t] = s;
    }
    __syncthreads();
    if (t >= 128) return;
    int layer = t >> 6;
    int c = t & 63;
    const float* W  = layer ? w1 : w0;
    const float* B  = layer ? b1 : b0;
    const float* G  = layer ? g1 : g0;
    const float* BE = layer ? be1 : be0;

    const double invE = 1.0 / (double)NE;
    double m[11], wv[11];
    for (int k = 0; k < 11; ++k) {
        m[k] = gs[k] * invE;
        wv[k] = (double)W[k * 64 + c];
    }
    double md = 0.0;
    for (int k = 0; k < 11; ++k) md += m[k] * wv[k];
    double s2 = 0.0;
    int p = 11;
    for (int k = 0; k < 11; ++k)
        for (int l = k; l < 11; ++l) {
            double Me = gs[p] * invE; ++p;
            double term = Me * wv[k] * wv[l];
            s2 += (k == l) ? term : 2.0 * term;
        }
    double var = s2 - md * md;
    double mu = md + (double)B[c];
    float scale = (float)((double)G[c] / sqrt(var + (double)EPS_BN));
    float shift = (float)((double)BE[c] - mu * (double)scale);

    float* wpd = wbp + layer * 768;
    for (int k = 0; k < 11; ++k) wpd[k * 64 + c] = W[k * 64 + c] * scale;
    wpd[704 + c] = fmaf(B[c], scale, shift);
}

// Pass 3a: per-block exclusive scan of deg -> rowptr (block-local) + block sums.
__global__ void __launch_bounds__(256) scanA_kernel(
    const int* __restrict__ deg, int* __restrict__ rowptr, int* __restrict__ bsum)
{
    int b = blockIdx.x, t = threadIdx.x;
    int i = b * 256 + t;
    int d = (i < NN) ? deg[i] : 0;
    __shared__ int sh[256];
    sh[t] = d;
    __syncthreads();
    for (int off = 1; off < 256; off <<= 1) {
        int val = (t >= off) ? sh[t - off] : 0;
        __syncthreads();
        sh[t] += val;
        __syncthreads();
    }
    if (i < NN) rowptr[i] = sh[t] - d;     // exclusive within block
    if (t == 255) bsum[b] = sh[255];
}

// Pass 3b: add block offsets in-place.
__global__ void __launch_bounds__(256) scanC_kernel(
    int* __restrict__ rowptr, const int* __restrict__ bsum)
{
    int b = blockIdx.x, t = threadIdx.x;
    __shared__ int sh[256];
    int s = 0;
    for (int j = t; j < b; j += 256) s += bsum[j];
    sh[t] = s;
    __syncthreads();
    for (int off = 128; off > 0; off >>= 1) {
        if (t < off) sh[t] += sh[t + off];
        __syncthreads();
    }
    int boff = sh[0];
    int i = b * 256 + t;
    if (i < NN) rowptr[i] += boff;
    if (b == 0 && t == 0) rowptr[NN] = NE;
}

// Pass 4: scatter edge records (src + bf16-packed edge_attr) into dst order.
__global__ void __launch_bounds__(256) scatter_kernel(
    const int* __restrict__ ei, const float* __restrict__ ea,
    int* __restrict__ cursor, int2* __restrict__ recs)
{
    int e = blockIdx.x * 256 + threadIdx.x;
    if (e >= NE) return;
    int s = ei[e];
    int d = ei[NE + e];
    float2 a2 = *(const float2*)(ea + 2 * (size_t)e);
    unsigned ua = __float_as_uint(a2.x), ub = __float_as_uint(a2.y);
    unsigned pa = (ua + 0x7fffu + ((ua >> 16) & 1u)) >> 16;   // rne bf16
    unsigned pb = (ub + 0x7fffu + ((ub >> 16) & 1u)) >> 16;
    int idx = atomicAdd(&cursor[d], 1);
    recs[idx] = make_int2(s, (int)((pa << 16) | pb));
}

// Degree-bucket counting sort, contention-free:
// bucketA: LDS histogram per block -> local rank + transposed block-hist matrix.
__global__ void __launch_bounds__(256) bucketA_kernel(
    const int* __restrict__ rowptr, int* __restrict__ pr, int* __restrict__ bhT)
{
    __shared__ int lh[64];
    int t = threadIdx.x, b = blockIdx.x;
    if (t < 64) lh[t] = 0;
    __syncthreads();
    int n = b * 256 + t;
    if (n < NN) {
        int d = rowptr[n + 1] - rowptr[n];
        int bkt = d < 63 ? d : 63;
        int lrank = atomicAdd(&lh[bkt], 1);     // LDS atomic: block-local only
        pr[n] = (lrank << 6) | bkt;
    }
    __syncthreads();
    if (t < 64) bhT[t * SCAN_BLOCKS + b] = lh[t];   // bucket-major layout
}

// Generic exclusive scan over bhT (bucket-major => scan yields global offsets).
__global__ void __launch_bounds__(256) gscanA_kernel(
    int* __restrict__ a, int* __restrict__ gbsum)
{
    int b = blockIdx.x, t = threadIdx.x;
    int i = b * 256 + t;
    int d = (i < GS_LEN) ? a[i] : 0;
    __shared__ int sh[256];
    sh[t] = d;
    __syncthreads();
    for (int off = 1; off < 256; off <<= 1) {
        int val = (t >= off) ? sh[t - off] : 0;
        __syncthreads();
        sh[t] += val;
        __syncthreads();
    }
    if (i < GS_LEN) a[i] = sh[t] - d;
    if (t == 255) gbsum[b] = sh[255];
}

__global__ void __launch_bounds__(256) gscanB_kernel(
    int* __restrict__ a, const int* __restrict__ gbsum)
{
    int b = blockIdx.x, t = threadIdx.x;
    __shared__ int sh[256];
    int s = 0;
    for (int j = t; j < b; j += 256) s += gbsum[j];
    sh[t] = s;
    __syncthreads();
    for (int off = 128; off > 0; off >>= 1) {
        if (t < off) sh[t] += sh[t + off];
        __syncthreads();
    }
    int boff = sh[0];
    int i = b * 256 + t;
    if (i < GS_LEN) a[i] += boff;
}

__global__ void __launch_bounds__(256) permB_kernel(
    const int* __restrict__ pr, const int* __restrict__ bhT, int* __restrict__ perm)
{
    int n = blockIdx.x * 256 + threadIdx.x;
    if (n >= NN) return;
    int p = pr[n];
    int bkt = p & 63, lrank = p >> 6, b = n >> 8;
    perm[bhT[bkt * SCAN_BLOCKS + b] + lrank] = n;
}

// Pass 5 (per layer): fused gather-message + mean + root + lrelu (+residual).
// 8 threads per dst node (degree-sorted); weights in registers.
template<int LAYER>
__global__ void __launch_bounds__(256) layer_kernel(
    const float* __restrict__ vres,
    const float* __restrict__ x,       // v for L0, v1 for L1
    const int2* __restrict__ recs,
    const int* __restrict__ rowptr,
    const int* __restrict__ perm,
    const float* __restrict__ wb,      // [768] W' then b'
    const float* __restrict__ rw, const float* __restrict__ rb,
    float* __restrict__ out)
{
    int g = blockIdx.x * 256 + threadIdx.x;   // g < 8*NN exactly
    int n = perm[g >> 3];
    int i = g & 7;

    float wreg[11][8];
#pragma unroll
    for (int k = 0; k < 11; ++k) {
        float4 wa = *(const float4*)(wb + k * 64 + i * 8);
        float4 wc = *(const float4*)(wb + k * 64 + i * 8 + 4);
        wreg[k][0] = wa.x; wreg[k][1] = wa.y; wreg[k][2] = wa.z; wreg[k][3] = wa.w;
        wreg[k][4] = wc.x; wreg[k][5] = wc.y; wreg[k][6] = wc.z; wreg[k][7] = wc.w;
    }
    float breg[8];
    {
        float4 ba = *(const float4*)(wb + 704 + i * 8);
        float4 bb = *(const float4*)(wb + 704 + i * 8 + 4);
        breg[0] = ba.x; breg[1] = ba.y; breg[2] = ba.z; breg[3] = ba.w;
        breg[4] = bb.x; breg[5] = bb.y; breg[6] = bb.z; breg[7] = bb.w;
    }

    float4 vd0 = *(const float4*)(vres + (size_t)n * 8);
    float4 vd1 = *(const float4*)(vres + (size_t)n * 8 + 4);
    float vd[8] = {vd0.x, vd0.y, vd0.z, vd0.w, vd1.x, vd1.y, vd1.z, vd1.w};

    float msg[8];
#pragma unroll
    for (int o = 0; o < 8; ++o) msg[o] = 0.0f;

    int rp0 = rowptr[n];
    int rp1 = rowptr[n + 1];
    for (int j = rp0; j < rp1; ++j) {
        int2 r = recs[j];
        int s = r.x;
        unsigned p = (unsigned)r.y;
        float e[11];
        e[0] = __uint_as_float(p & 0xffff0000u);
        e[1] = __uint_as_float(p << 16);
        float4 s0 = *(const float4*)(vres + (size_t)s * 8);
        float4 s1 = *(const float4*)(vres + (size_t)s * 8 + 4);
        float xi = x[(size_t)s * 8 + i];

        float df[8];
        df[0] = vd[0] - s0.x; df[1] = vd[1] - s0.y;
        df[2] = vd[2] - s0.z; df[3] = vd[3] - s0.w;
        df[4] = vd[4] - s1.x; df[5] = vd[5] - s1.y;
        df[6] = vd[6] - s1.z; df[7] = vd[7] - s1.w;
        float nsq = 0.0f;
#pragma unroll
        for (int q = 0; q < 8; ++q) nsq = fmaf(df[q], df[q], nsq);
        float nrm = sqrtf(nsq);
        float invn = __builtin_amdgcn_rcpf(nrm + EPS_NORM);
        e[2] = nrm;
#pragma unroll
        for (int q = 0; q < 8; ++q) e[3 + q] = df[q] * invn;

#pragma unroll
        for (int o = 0; o < 8; ++o) {
            float hh = breg[o];
#pragma unroll
            for (int k = 0; k < 11; ++k) hh = fmaf(e[k], wreg[k][o], hh);
            msg[o] = fmaf(xi, fast_tanh(hh), msg[o]);
        }
    }

    // sum partial msg over the 8 lanes of this node-group
#pragma unroll
    for (int o = 0; o < 8; ++o) {
        float m = msg[o];
        m += __shfl_xor(m, 1);
        m += __shfl_xor(m, 2);
        m += __shfl_xor(m, 4);
        msg[o] = m;
    }
    float mo = msg[0];
#pragma unroll
    for (int o = 1; o < 8; ++o) if (i == o) mo = msg[o];

    float cf = (float)(rp1 - rp0);
    float invc = __builtin_amdgcn_rcpf(fmaxf(cf, 1.0f));

    float xn[8];
    if (LAYER == 0) {
#pragma unroll
        for (int q = 0; q < 8; ++q) xn[q] = vd[q];
    } else {
        float4 x0 = *(const float4*)(x + (size_t)n * 8);
        float4 x1 = *(const float4*)(x + (size_t)n * 8 + 4);
        xn[0] = x0.x; xn[1] = x0.y; xn[2] = x0.z; xn[3] = x0.w;
        xn[4] = x1.x; xn[5] = x1.y; xn[6] = x1.z; xn[7] = x1.w;
    }
    float a = fmaf(mo, invc, rb[i]);
#pragma unroll
    for (int k = 0; k < 8; ++k) a = fmaf(xn[k], rw[k * 8 + i], a);
    float y = (a > 0.0f) ? a : SLOPE * a;
    if (LAYER == 1) y += vres[(size_t)n * 8 + i];
    out[(size_t)n * 8 + i] = y;
}

extern "C" void kernel_launch(void* const* d_in, const int* in_sizes, int n_in,
                              void* d_out, int out_size, void* d_ws, size_t ws_size,
                              hipStream_t stream) {
    const float* v  = (const float*)d_in[0];
    const int* ei   = (const int*)d_in[1];
    const float* ea = (const float*)d_in[2];
    const float* en_w0  = (const float*)d_in[3];
    const float* en_b0  = (const float*)d_in[4];
    const float* en_g0  = (const float*)d_in[5];
    const float* en_be0 = (const float*)d_in[6];
    const float* rw0    = (const float*)d_in[7];
    const float* rb0    = (const float*)d_in[8];
    const float* en_w1  = (const float*)d_in[9];
    const float* en_b1  = (const float*)d_in[10];
    const float* en_g1  = (const float*)d_in[11];
    const float* en_be1 = (const float*)d_in[12];
    const float* rw1    = (const float*)d_in[13];
    const float* rb1    = (const float*)d_in[14];

    char* ws = (char*)d_ws;
    float* partials = (float*)(ws);                   // 157,696 B
    float* wbp      = (float*)(ws + 163840);          // 6,144 B
    int*   deg      = (int*)  (ws + 172032);          // 400,000 B
    int*   rowptr   = (int*)  (ws + 573440);          // 400,004 B
    int*   bsum     = (int*)  (ws + 974848);          // 1,564 B
    int*   pr       = (int*)  (ws + 976896);          // 400,000 B
    int*   perm     = (int*)  (ws + 1377280);         // 400,000 B
    int*   cursor   = (int*)  (ws + 1777664);         // 400,000 B
    int*   bhT      = (int*)  (ws + 2177664);         // 100,096 B
    int*   gbsum    = (int*)  (ws + 2277760);         // 392 B
    float* v1       = (float*)(ws + 2281472);         // 3,200,000 B
    int2*  recs     = (int2*) (ws + 5484544);         // 12,800,000 B (end ~18.3 MB)
    float* vout     = (float*)d_out;

    hipMemsetAsync(deg, 0, NN * sizeof(int), stream);

    stats_kernel<<<STATS_BLOCKS, 256, 0, stream>>>(v, ei, ea, partials, deg);
    bn_finalize_kernel<<<1, 128, 0, stream>>>(partials, en_w0, en_b0, en_g0, en_be0,
                                              en_w1, en_b1, en_g1, en_be1, wbp);
    scanA_kernel<<<SCAN_BLOCKS, 256, 0, stream>>>(deg, rowptr, bsum);
    scanC_kernel<<<SCAN_BLOCKS, 256, 0, stream>>>(rowptr, bsum);
    hipMemcpyAsync(cursor, rowptr, NN * sizeof(int), hipMemcpyDeviceToDevice, stream);
    scatter_kernel<<<(NE + 255) / 256, 256, 0, stream>>>(ei, ea, cursor, recs);
    bucketA_kernel<<<SCAN_BLOCKS, 256, 0, stream>>>(rowptr, pr, bhT);
    gscanA_kernel<<<GS_BLOCKS, 256, 0, stream>>>(bhT, gbsum);
    gscanB_kernel<<<GS_BLOCKS, 256, 0, stream>>>(bhT, gbsum);
    permB_kernel<<<SCAN_BLOCKS, 256, 0, stream>>>(pr, bhT, perm);

    const int LB = (NN * 8) / 256;   // 3125, exact
    layer_kernel<0><<<LB, 256, 0, stream>>>(v, v,  recs, rowptr, perm, wbp,       rw0, rb0, v1);
    layer_kernel<1><<<LB, 256, 0, stream>>>(v, v1, recs, rowptr, perm, wbp + 768, rw1, rb1, vout);
}

// Round 7
// 401.276 us; speedup vs baseline: 1.8098x; 1.1483x over previous
//
#include <hip/hip_runtime.h>
#include <math.h>

#define NN 100000
#define NE 1600000
#define EPS_BN 1e-5f
#define EPS_NORM 1e-12f
#define SLOPE 0.01f
#define STATS_BLOCKS 512
#define SCAN_BLOCKS ((NN + 255) / 256)       // 391
#define GS_LEN (64 * SCAN_BLOCKS)            // 25024
#define GS_BLOCKS ((GS_LEN + 255) / 256)     // 98

__device__ __forceinline__ float fast_tanh(float x) {
    // tanh(x) = 1 - 2/(exp2(x*2*log2e)+1); exact saturation at +-inf
    float t = exp2f(x * 2.885390082f);
    return fmaf(-2.0f, __builtin_amdgcn_rcpf(t + 1.0f), 1.0f);
}

// Pass 0: in-degree histogram (int4-vectorized edge-dst read).
__global__ void __launch_bounds__(256) deg_kernel(
    const int* __restrict__ ei, int* __restrict__ deg)
{
    int t = blockIdx.x * 256 + threadIdx.x;
    if (t * 4 >= NE) return;
    int4 d4 = *(const int4*)(ei + NE + t * 4);
    atomicAdd(&deg[d4.x], 1);
    atomicAdd(&deg[d4.y], 1);
    atomicAdd(&deg[d4.z], 1);
    atomicAdd(&deg[d4.w], 1);
}

// Pass 1a: per-block exclusive scan of deg -> rowptr (block-local) + block sums.
__global__ void __launch_bounds__(256) scanA_kernel(
    const int* __restrict__ deg, int* __restrict__ rowptr, int* __restrict__ bsum)
{
    int b = blockIdx.x, t = threadIdx.x;
    int i = b * 256 + t;
    int d = (i < NN) ? deg[i] : 0;
    __shared__ int sh[256];
    sh[t] = d;
    __syncthreads();
    for (int off = 1; off < 256; off <<= 1) {
        int val = (t >= off) ? sh[t - off] : 0;
        __syncthreads();
        sh[t] += val;
        __syncthreads();
    }
    if (i < NN) rowptr[i] = sh[t] - d;     // exclusive within block
    if (t == 255) bsum[b] = sh[255];
}

// Pass 1b: add block offsets in-place.
__global__ void __launch_bounds__(256) scanC_kernel(
    int* __restrict__ rowptr, const int* __restrict__ bsum)
{
    int b = blockIdx.x, t = threadIdx.x;
    __shared__ int sh[256];
    int s = 0;
    for (int j = t; j < b; j += 256) s += bsum[j];
    sh[t] = s;
    __syncthreads();
    for (int off = 128; off > 0; off >>= 1) {
        if (t < off) sh[t] += sh[t + off];
        __syncthreads();
    }
    int boff = sh[0];
    int i = b * 256 + t;
    if (i < NN) rowptr[i] += boff;
    if (b == 0 && t == 0) rowptr[NN] = NE;
}

// Pass 2: FUSED scatter + e-moment stats. One gather pass over all edges:
// computes e, accumulates 77 moments, packs edge_attr to bf16, writes
// dst-sorted edge records via per-dst cursor atomics.
__global__ void __launch_bounds__(256) scatstat_kernel(
    const float* __restrict__ v,
    const int* __restrict__ ei,
    const float* __restrict__ ea,
    int* __restrict__ cursor,
    int2* __restrict__ recs,
    float* __restrict__ partials)   // [STATS_BLOCKS][77]
{
    float acc[77];
#pragma unroll
    for (int i = 0; i < 77; ++i) acc[i] = 0.0f;

    int tid = blockIdx.x * blockDim.x + threadIdx.x;
    int stride = gridDim.x * blockDim.x;
    for (int eidx = tid; eidx < NE; eidx += stride) {
        int s = ei[eidx];
        int d = ei[NE + eidx];
        float2 a2 = *(const float2*)(ea + 2 * (size_t)eidx);

        float4 s0 = *(const float4*)(v + (size_t)s * 8);
        float4 s1 = *(const float4*)(v + (size_t)s * 8 + 4);
        float4 d0 = *(const float4*)(v + (size_t)d * 8);
        float4 d1 = *(const float4*)(v + (size_t)d * 8 + 4);
        float df[8];
        df[0] = d0.x - s0.x; df[1] = d0.y - s0.y;
        df[2] = d0.z - s0.z; df[3] = d0.w - s0.w;
        df[4] = d1.x - s1.x; df[5] = d1.y - s1.y;
        df[6] = d1.z - s1.z; df[7] = d1.w - s1.w;
        float nsq = 0.0f;
#pragma unroll
        for (int i = 0; i < 8; ++i) nsq = fmaf(df[i], df[i], nsq);
        float nrm = sqrtf(nsq);
        float inv = __builtin_amdgcn_rcpf(nrm + EPS_NORM);
        float e[11];
        e[0] = a2.x; e[1] = a2.y; e[2] = nrm;
#pragma unroll
        for (int i = 0; i < 8; ++i) e[3 + i] = df[i] * inv;

        int p = 11;
#pragma unroll
        for (int k = 0; k < 11; ++k) {
            acc[k] += e[k];
#pragma unroll
            for (int l = k; l < 11; ++l) { acc[p] = fmaf(e[k], e[l], acc[p]); ++p; }
        }

        unsigned ua = __float_as_uint(a2.x), ub = __float_as_uint(a2.y);
        unsigned pa = (ua + 0x7fffu + ((ua >> 16) & 1u)) >> 16;   // rne bf16
        unsigned pb = (ub + 0x7fffu + ((ub >> 16) & 1u)) >> 16;
        int idx = atomicAdd(&cursor[d], 1);
        recs[idx] = make_int2(s, (int)((pa << 16) | pb));
    }

#pragma unroll
    for (int i = 0; i < 77; ++i) {
        float x = acc[i];
        for (int off = 32; off > 0; off >>= 1) x += __shfl_down(x, off);
        acc[i] = x;
    }
    __shared__ float lsum[4][77];
    int wave = threadIdx.x >> 6;
    int lane = threadIdx.x & 63;
    if (lane == 0) {
#pragma unroll
        for (int i = 0; i < 77; ++i) lsum[wave][i] = acc[i];
    }
    __syncthreads();
    if (threadIdx.x < 77) {
        float t = lsum[0][threadIdx.x] + lsum[1][threadIdx.x]
                + lsum[2][threadIdx.x] + lsum[3][threadIdx.x];
        partials[blockIdx.x * 77 + threadIdx.x] = t;
    }
}

// Pass 3: reduce partials, closed-form BN, fold scale into W' and b'.
__global__ void bn_finalize_kernel(
    const float* __restrict__ partials,
    const float* __restrict__ w0, const float* __restrict__ b0,
    const float* __restrict__ g0, const float* __restrict__ be0,
    const float* __restrict__ w1, const float* __restrict__ b1,
    const float* __restrict__ g1, const float* __restrict__ be1,
    float* __restrict__ wbp)   // layer l at +l*768: W'[704] then b'[64]
{
    __shared__ double gs[77];
    int t = threadIdx.x;
    if (t < 77) {
        double s = 0.0;
        for (int b = 0; b < STATS_BLOCKS; ++b) s += (double)partials[b * 77 + t];
        gs[t] = s;
    }
    __syncthreads();
    if (t >= 128) return;
    int layer = t >> 6;
    int c = t & 63;
    const float* W  = layer ? w1 : w0;
    const float* B  = layer ? b1 : b0;
    const float* G  = layer ? g1 : g0;
    const float* BE = layer ? be1 : be0;

    const double invE = 1.0 / (double)NE;
    double m[11], wv[11];
    for (int k = 0; k < 11; ++k) {
        m[k] = gs[k] * invE;
        wv[k] = (double)W[k * 64 + c];
    }
    double md = 0.0;
    for (int k = 0; k < 11; ++k) md += m[k] * wv[k];
    double s2 = 0.0;
    int p = 11;
    for (int k = 0; k < 11; ++k)
        for (int l = k; l < 11; ++l) {
            double Me = gs[p] * invE; ++p;
            double term = Me * wv[k] * wv[l];
            s2 += (k == l) ? term : 2.0 * term;
        }
    double var = s2 - md * md;
    double mu = md + (double)B[c];
    float scale = (float)((double)G[c] / sqrt(var + (double)EPS_BN));
    float shift = (float)((double)BE[c] - mu * (double)scale);

    float* wpd = wbp + layer * 768;
    for (int k = 0; k < 11; ++k) wpd[k * 64 + c] = W[k * 64 + c] * scale;
    wpd[704 + c] = fmaf(B[c], scale, shift);
}

// Degree-bucket counting sort (DESCENDING: heavy nodes first -> LPT schedule).
__global__ void __launch_bounds__(256) bucketA_kernel(
    const int* __restrict__ rowptr, int* __restrict__ pr, int* __restrict__ bhT)
{
    __shared__ int lh[64];
    int t = threadIdx.x, b = blockIdx.x;
    if (t < 64) lh[t] = 0;
    __syncthreads();
    int n = b * 256 + t;
    if (n < NN) {
        int d = rowptr[n + 1] - rowptr[n];
        int db = d < 63 ? d : 63;
        int bkt = 63 - db;                      // descending degree order
        int lrank = atomicAdd(&lh[bkt], 1);     // LDS atomic: block-local only
        pr[n] = (lrank << 6) | bkt;
    }
    __syncthreads();
    if (t < 64) bhT[t * SCAN_BLOCKS + b] = lh[t];   // bucket-major layout
}

// Generic exclusive scan over bhT (bucket-major => scan yields global offsets).
__global__ void __launch_bounds__(256) gscanA_kernel(
    int* __restrict__ a, int* __restrict__ gbsum)
{
    int b = blockIdx.x, t = threadIdx.x;
    int i = b * 256 + t;
    int d = (i < GS_LEN) ? a[i] : 0;
    __shared__ int sh[256];
    sh[t] = d;
    __syncthreads();
    for (int off = 1; off < 256; off <<= 1) {
        int val = (t >= off) ? sh[t - off] : 0;
        __syncthreads();
        sh[t] += val;
        __syncthreads();
    }
    if (i < GS_LEN) a[i] = sh[t] - d;
    if (t == 255) gbsum[b] = sh[255];
}

__global__ void __launch_bounds__(256) gscanB_kernel(
    int* __restrict__ a, const int* __restrict__ gbsum)
{
    int b = blockIdx.x, t = threadIdx.x;
    __shared__ int sh[256];
    int s = 0;
    for (int j = t; j < b; j += 256) s += gbsum[j];
    sh[t] = s;
    __syncthreads();
    for (int off = 128; off > 0; off >>= 1) {
        if (t < off) sh[t] += sh[t + off];
        __syncthreads();
    }
    int boff = sh[0];
    int i = b * 256 + t;
    if (i < GS_LEN) a[i] += boff;
}

// Emit int4 perm records {node, rowptr[n], rowptr[n+1], 0}.
__global__ void __launch_bounds__(256) permB_kernel(
    const int* __restrict__ pr, const int* __restrict__ bhT,
    const int* __restrict__ rowptr, int4* __restrict__ perm4)
{
    int n = blockIdx.x * 256 + threadIdx.x;
    if (n >= NN) return;
    int p = pr[n];
    int bkt = p & 63, lrank = p >> 6, b = n >> 8;
    int pos = bhT[bkt * SCAN_BLOCKS + b] + lrank;
    perm4[pos] = make_int4(n, rowptr[n], rowptr[n + 1], 0);
}

// Pass 5 (per layer): fused gather-message + mean + root + lrelu (+residual).
// 8 threads per dst node (degree-sorted desc); weights in registers;
// next-edge rec + x prefetched one iteration ahead.
template<int LAYER>
__global__ void __launch_bounds__(256) layer_kernel(
    const float* __restrict__ vres,
    const float* __restrict__ x,       // v for L0, v1 for L1
    const int2* __restrict__ recs,
    const int4* __restrict__ perm4,
    const float* __restrict__ wb,      // [768] W' then b'
    const float* __restrict__ rw, const float* __restrict__ rb,
    float* __restrict__ out)
{
    int g = blockIdx.x * 256 + threadIdx.x;   // g < 8*NN exactly
    int4 pm = perm4[g >> 3];
    int n = pm.x, rp0 = pm.y, rp1 = pm.z;
    int i = g & 7;

    float wreg[11][8];
#pragma unroll
    for (int k = 0; k < 11; ++k) {
        float4 wa = *(const float4*)(wb + k * 64 + i * 8);
        float4 wc = *(const float4*)(wb + k * 64 + i * 8 + 4);
        wreg[k][0] = wa.x; wreg[k][1] = wa.y; wreg[k][2] = wa.z; wreg[k][3] = wa.w;
        wreg[k][4] = wc.x; wreg[k][5] = wc.y; wreg[k][6] = wc.z; wreg[k][7] = wc.w;
    }
    float breg[8];
    {
        float4 ba = *(const float4*)(wb + 704 + i * 8);
        float4 bb = *(const float4*)(wb + 704 + i * 8 + 4);
        breg[0] = ba.x; breg[1] = ba.y; breg[2] = ba.z; breg[3] = ba.w;
        breg[4] = bb.x; breg[5] = bb.y; breg[6] = bb.z; breg[7] = bb.w;
    }

    float4 vd0 = *(const float4*)(vres + (size_t)n * 8);
    float4 vd1 = *(const float4*)(vres + (size_t)n * 8 + 4);
    float vd[8] = {vd0.x, vd0.y, vd0.z, vd0.w, vd1.x, vd1.y, vd1.z, vd1.w};

    float msg[8];
#pragma unroll
    for (int o = 0; o < 8; ++o) msg[o] = 0.0f;

    if (rp0 < rp1) {
        int2 r = recs[rp0];
        float xi = x[(size_t)r.x * 8 + i];
        for (int j = rp0; j < rp1; ++j) {
            bool has = (j + 1 < rp1);
            int2 rn = has ? recs[j + 1] : r;                 // prefetch rec
            float xin = has ? x[(size_t)rn.x * 8 + i] : xi;  // prefetch x

            float4 s0 = *(const float4*)(vres + (size_t)r.x * 8);
            float4 s1 = *(const float4*)(vres + (size_t)r.x * 8 + 4);
            unsigned p = (unsigned)r.y;
            float e[11];
            e[0] = __uint_as_float(p & 0xffff0000u);
            e[1] = __uint_as_float(p << 16);

            float df[8];
            df[0] = vd[0] - s0.x; df[1] = vd[1] - s0.y;
            df[2] = vd[2] - s0.z; df[3] = vd[3] - s0.w;
            df[4] = vd[4] - s1.x; df[5] = vd[5] - s1.y;
            df[6] = vd[6] - s1.z; df[7] = vd[7] - s1.w;
            float nsq = 0.0f;
#pragma unroll
            for (int q = 0; q < 8; ++q) nsq = fmaf(df[q], df[q], nsq);
            float nrm = sqrtf(nsq);
            float invn = __builtin_amdgcn_rcpf(nrm + EPS_NORM);
            e[2] = nrm;
#pragma unroll
            for (int q = 0; q < 8; ++q) e[3 + q] = df[q] * invn;

#pragma unroll
            for (int o = 0; o < 8; ++o) {
                float hh = breg[o];
#pragma unroll
                for (int k = 0; k < 11; ++k) hh = fmaf(e[k], wreg[k][o], hh);
                msg[o] = fmaf(xi, fast_tanh(hh), msg[o]);
            }

            r = rn; xi = xin;
        }
    }

    // sum partial msg over the 8 lanes of this node-group
#pragma unroll
    for (int o = 0; o < 8; ++o) {
        float m = msg[o];
        m += __shfl_xor(m, 1);
        m += __shfl_xor(m, 2);
        m += __shfl_xor(m, 4);
        msg[o] = m;
    }
    float mo = msg[0];
#pragma unroll
    for (int o = 1; o < 8; ++o) if (i == o) mo = msg[o];

    float cf = (float)(rp1 - rp0);
    float invc = __builtin_amdgcn_rcpf(fmaxf(cf, 1.0f));

    float xn[8];
    if (LAYER == 0) {
#pragma unroll
        for (int q = 0; q < 8; ++q) xn[q] = vd[q];
    } else {
        float4 x0 = *(const float4*)(x + (size_t)n * 8);
        float4 x1 = *(const float4*)(x + (size_t)n * 8 + 4);
        xn[0] = x0.x; xn[1] = x0.y; xn[2] = x0.z; xn[3] = x0.w;
        xn[4] = x1.x; xn[5] = x1.y; xn[6] = x1.z; xn[7] = x1.w;
    }
    float a = fmaf(mo, invc, rb[i]);
#pragma unroll
    for (int k = 0; k < 8; ++k) a = fmaf(xn[k], rw[k * 8 + i], a);
    float y = (a > 0.0f) ? a : SLOPE * a;
    if (LAYER == 1) y += vres[(size_t)n * 8 + i];
    out[(size_t)n * 8 + i] = y;
}

extern "C" void kernel_launch(void* const* d_in, const int* in_sizes, int n_in,
                              void* d_out, int out_size, void* d_ws, size_t ws_size,
                              hipStream_t stream) {
    const float* v  = (const float*)d_in[0];
    const int* ei   = (const int*)d_in[1];
    const float* ea = (const float*)d_in[2];
    const float* en_w0  = (const float*)d_in[3];
    const float* en_b0  = (const float*)d_in[4];
    const float* en_g0  = (const float*)d_in[5];
    const float* en_be0 = (const float*)d_in[6];
    const float* rw0    = (const float*)d_in[7];
    const float* rb0    = (const float*)d_in[8];
    const float* en_w1  = (const float*)d_in[9];
    const float* en_b1  = (const float*)d_in[10];
    const float* en_g1  = (const float*)d_in[11];
    const float* en_be1 = (const float*)d_in[12];
    const float* rw1    = (const float*)d_in[13];
    const float* rb1    = (const float*)d_in[14];

    char* ws = (char*)d_ws;
    float* partials = (float*)(ws);                   // 157,696 B
    float* wbp      = (float*)(ws + 163840);          // 6,144 B
    int*   deg      = (int*)  (ws + 172032);          // 400,000 B
    int*   rowptr   = (int*)  (ws + 573440);          // 400,004 B
    int*   bsum     = (int*)  (ws + 974848);          // 1,564 B
    int*   pr       = (int*)  (ws + 978944);          // 400,000 B
    int4*  perm4    = (int4*) (ws + 1380352);         // 1,600,000 B
    int*   cursor   = (int*)  (ws + 2981888);         // 400,000 B
    int*   bhT      = (int*)  (ws + 3381888);         // 100,096 B
    int*   gbsum    = (int*)  (ws + 3482624);         // 392 B
    float* v1       = (float*)(ws + 3483648);         // 3,200,000 B
    int2*  recs     = (int2*) (ws + 6684672);         // 12,800,000 B (end ~19.5 MB)
    float* vout     = (float*)d_out;

    hipMemsetAsync(deg, 0, NN * sizeof(int), stream);

    deg_kernel<<<(NE / 4 + 255) / 256, 256, 0, stream>>>(ei, deg);
    scanA_kernel<<<SCAN_BLOCKS, 256, 0, stream>>>(deg, rowptr, bsum);
    scanC_kernel<<<SCAN_BLOCKS, 256, 0, stream>>>(rowptr, bsum);
    hipMemcpyAsync(cursor, rowptr, NN * sizeof(int), hipMemcpyDeviceToDevice, stream);
    scatstat_kernel<<<STATS_BLOCKS, 256, 0, stream>>>(v, ei, ea, cursor, recs, partials);
    bn_finalize_kernel<<<1, 128, 0, stream>>>(partials, en_w0, en_b0, en_g0, en_be0,
                                              en_w1, en_b1, en_g1, en_be1, wbp);
    bucketA_kernel<<<SCAN_BLOCKS, 256, 0, stream>>>(rowptr, pr, bhT);
    gscanA_kernel<<<GS_BLOCKS, 256, 0, stream>>>(bhT, gbsum);
    gscanB_kernel<<<GS_BLOCKS, 256, 0, stream>>>(bhT, gbsum);
    permB_kernel<<<SCAN_BLOCKS, 256, 0, stream>>>(pr, bhT, rowptr, perm4);

    const int LB = (NN * 8) / 256;   // 3125, exact
    layer_kernel<0><<<LB, 256, 0, stream>>>(v, v,  recs, perm4, wbp,       rw0, rb0, v1);
    layer_kernel<1><<<LB, 256, 0, stream>>>(v, v1, recs, perm4, wbp + 768, rw1, rb1, vout);
}